// Round 5
// baseline (1329.277 us; speedup 1.0000x reference)
//
#include <hip/hip_runtime.h>
#include <math.h>

namespace {

constexpr int B   = 2;
constexpr int S   = 2048;
constexpr int D   = 2048;
constexpr int NH  = 16;
constexpr int NKV = 4;
constexpr int HD  = 128;
constexpr int GRP = NH / NKV;   // 4

typedef __attribute__((ext_vector_type(8))) short  short8;
typedef __attribute__((ext_vector_type(4))) float  f32x4;
typedef unsigned short u16;

__device__ inline u16 f2bf(float f) {
    unsigned u = __float_as_uint(f);
    u = (u + 0x7FFFu + ((u >> 16) & 1u)) >> 16;   // RNE
    return (u16)u;
}
__device__ inline float bf2f(u16 h) {
    return __uint_as_float((unsigned)h << 16);
}

// async global->LDS, 16B per lane; LDS dest = wave-uniform base + lane*16.
__device__ __forceinline__ void gload_lds16(const void* g, void* l) {
    __builtin_amdgcn_global_load_lds(
        (const __attribute__((address_space(1))) unsigned int*)g,
        (__attribute__((address_space(3))) unsigned int*)l, 16, 0, 0);
}

// ---------------------------------------------------------------------------
// split-cast fp32 -> (bf16 hi, bf16 lo), elementwise, float4-vectorized.
// ---------------------------------------------------------------------------
__global__ __launch_bounds__(256)
void split_cast_kernel(const float* __restrict__ X, u16* __restrict__ H,
                       u16* __restrict__ L, int n4)
{
    const int idx = blockIdx.x * 256 + threadIdx.x;
    if (idx >= n4) return;
    const float4 v = reinterpret_cast<const float4*>(X)[idx];
    ushort4 h, l;
    h.x = f2bf(v.x); l.x = f2bf(v.x - bf2f(h.x));
    h.y = f2bf(v.y); l.y = f2bf(v.y - bf2f(h.y));
    h.z = f2bf(v.z); l.z = f2bf(v.z - bf2f(h.z));
    h.w = f2bf(v.w); l.w = f2bf(v.w - bf2f(h.w));
    reinterpret_cast<ushort4*>(H)[idx] = h;
    reinterpret_cast<ushort4*>(L)[idx] = l;
}

// ---------------------------------------------------------------------------
// Weight transpose-cast: W [K=2048][Nw] fp32 -> T hi/lo [n_off+Nw][2048] bf16.
// ---------------------------------------------------------------------------
__global__ __launch_bounds__(256)
void wcast_t_kernel(const float* __restrict__ W, u16* __restrict__ Th,
                    u16* __restrict__ Tl, int Nw, int n_off)
{
    __shared__ u16 th[64][68];
    __shared__ u16 tl[64][68];
    const int t  = threadIdx.x;
    const int n0 = blockIdx.x * 64;
    const int k0 = blockIdx.y * 64;

#pragma unroll
    for (int i = 0; i < 4; ++i) {
        const int kr = (t >> 4) + i * 16;
        const int nc = (t & 15) * 4;
        const float4 v = *reinterpret_cast<const float4*>(
            &W[(size_t)(k0 + kr) * Nw + n0 + nc]);
        const u16 hx = f2bf(v.x), hy = f2bf(v.y), hz = f2bf(v.z), hw = f2bf(v.w);
        th[kr][nc + 0] = hx; tl[kr][nc + 0] = f2bf(v.x - bf2f(hx));
        th[kr][nc + 1] = hy; tl[kr][nc + 1] = f2bf(v.y - bf2f(hy));
        th[kr][nc + 2] = hz; tl[kr][nc + 2] = f2bf(v.z - bf2f(hz));
        th[kr][nc + 3] = hw; tl[kr][nc + 3] = f2bf(v.w - bf2f(hw));
    }
    __syncthreads();
#pragma unroll
    for (int i = 0; i < 4; ++i) {
        const int nr = (t >> 4) + i * 16;
        const int kc = (t & 15) * 4;
        ushort4 oh, ol;
        oh.x = th[kc + 0][nr]; ol.x = tl[kc + 0][nr];
        oh.y = th[kc + 1][nr]; ol.y = tl[kc + 1][nr];
        oh.z = th[kc + 2][nr]; ol.z = tl[kc + 2][nr];
        oh.w = th[kc + 3][nr]; ol.w = tl[kc + 3][nr];
        const size_t o = (size_t)(n_off + n0 + nr) * 2048 + k0 + kc;
        *reinterpret_cast<ushort4*>(&Th[o]) = oh;
        *reinterpret_cast<ushort4*>(&Tl[o]) = ol;
    }
}

// ---------------------------------------------------------------------------
// hi/lo double-bf16 MFMA GEMM: C = A.B^T, fp32 out. (unchanged from round 4)
// ---------------------------------------------------------------------------
__global__ __launch_bounds__(256)
void hgemm_hilo_kernel(const u16* __restrict__ Ah, const u16* __restrict__ Al,
                       const u16* __restrict__ Bth, const u16* __restrict__ Btl,
                       float* __restrict__ C, int M, int N, int K)
{
    __shared__ alignas(16) u16 AsH[4096];
    __shared__ alignas(16) u16 AsL[4096];
    __shared__ alignas(16) u16 BsH[4096];
    __shared__ alignas(16) u16 BsL[4096];

    const int t  = threadIdx.x;
    const int w  = t >> 6;
    const int l  = t & 63;
    const int lc = l & 15;
    const int kg = l >> 4;
    const int wr = w >> 1, wc = w & 1;

    const int m0 = blockIdx.y * 128;
    const int n0 = blockIdx.x * 128;

    const int srow = l >> 2;
    const int sblk = l & 3;

    f32x4 acc[4][4];
#pragma unroll
    for (int i = 0; i < 4; ++i)
#pragma unroll
        for (int j = 0; j < 4; ++j) acc[i][j] = (f32x4){0.f, 0.f, 0.f, 0.f};

    for (int k0 = 0; k0 < K; k0 += 32) {
#pragma unroll
        for (int i = 0; i < 2; ++i) {
            const int c   = i * 4 + w;
            const int row = c * 16 + srow;
            const int swb = sblk ^ ((row >> 1) & 3);
            const size_t ga = (size_t)(m0 + row) * K + k0 + swb * 8;
            const size_t gb = (size_t)(n0 + row) * K + k0 + swb * 8;
            gload_lds16(Ah  + ga, AsH + c * 512);
            gload_lds16(Al  + ga, AsL + c * 512);
            gload_lds16(Bth + gb, BsH + c * 512);
            gload_lds16(Btl + gb, BsL + c * 512);
        }
        __syncthreads();

        short8 fah[4], fal[4], fbh[4], fbl[4];
#pragma unroll
        for (int i = 0; i < 4; ++i) {
            const int ra = wr * 64 + i * 16 + lc;
            const int oa = ra * 32 + ((kg ^ ((ra >> 1) & 3)) * 8);
            fah[i] = *reinterpret_cast<const short8*>(&AsH[oa]);
            fal[i] = *reinterpret_cast<const short8*>(&AsL[oa]);
            const int rb = wc * 64 + i * 16 + lc;
            const int ob = rb * 32 + ((kg ^ ((rb >> 1) & 3)) * 8);
            fbh[i] = *reinterpret_cast<const short8*>(&BsH[ob]);
            fbl[i] = *reinterpret_cast<const short8*>(&BsL[ob]);
        }
#pragma unroll
        for (int i = 0; i < 4; ++i)
#pragma unroll
            for (int j = 0; j < 4; ++j) {
                acc[i][j] = __builtin_amdgcn_mfma_f32_16x16x32_bf16(
                    fal[i], fbh[j], acc[i][j], 0, 0, 0);
                acc[i][j] = __builtin_amdgcn_mfma_f32_16x16x32_bf16(
                    fah[i], fbl[j], acc[i][j], 0, 0, 0);
                acc[i][j] = __builtin_amdgcn_mfma_f32_16x16x32_bf16(
                    fah[i], fbh[j], acc[i][j], 0, 0, 0);
            }
        __syncthreads();
    }

#pragma unroll
    for (int i = 0; i < 4; ++i)
#pragma unroll
        for (int j = 0; j < 4; ++j)
#pragma unroll
            for (int r = 0; r < 4; ++r) {
                const int m = m0 + wr * 64 + i * 16 + kg * 4 + r;
                const int n = n0 + wc * 64 + j * 16 + lc;
                C[(size_t)m * N + n] = acc[i][j][r];
            }
}

// ---------------------------------------------------------------------------
// RoPE + split-cast fp32 -> bf16 hi/lo, head-major [B][nh][S][HD].
// ---------------------------------------------------------------------------
__global__ __launch_bounds__(256)
void rope_cast_kernel(const float* __restrict__ X, int stride, int col_off,
                      u16* __restrict__ Yh, u16* __restrict__ Yl,
                      int n_heads, int total_pairs, float scale)
{
    const int idx = blockIdx.x * 256 + threadIdx.x;
    if (idx >= total_pairs) return;
    const int i    = idx & 63;
    const int rest = idx >> 6;
    const int head = rest % n_heads;
    const int row  = rest / n_heads;
    const int s    = row & (S - 1);
    const int b    = row >> 11;

    const float inv = expf(-9.2103403719761836f * (float)i * (1.0f / 64.0f));
    float sn, cs;
    sincosf((float)s * inv, &sn, &cs);

    const float* src = X + (size_t)row * stride + col_off + head * HD + i;
    const float x1 = src[0], x2 = src[64];
    const float y1 = (x1 * cs - x2 * sn) * scale;
    const float y2 = (x2 * cs + x1 * sn) * scale;

    const u16 h1 = f2bf(y1), h2 = f2bf(y2);
    const size_t o = ((size_t)(b * n_heads + head) * S + s) * HD + i;
    Yh[o] = h1;  Yh[o + 64] = h2;
    Yl[o]      = f2bf(y1 - bf2f(h1));
    Yl[o + 64] = f2bf(y2 - bf2f(h2));
}

// ---------------------------------------------------------------------------
// V: fp32 (from fused QKV buffer) -> bf16 hi/lo transposed [B][NKV][HD][S].
// ---------------------------------------------------------------------------
__global__ __launch_bounds__(256)
void vcast_kernel(const float* __restrict__ V, int stride, int col_off,
                  u16* __restrict__ Yh, u16* __restrict__ Yl)
{
    __shared__ u16 th[64][68];
    __shared__ u16 tl[64][68];
    const int t  = threadIdx.x;
    const int s0 = blockIdx.x * 64, dv0 = blockIdx.y * 64;
    const int b  = blockIdx.z >> 2, u = blockIdx.z & 3;

#pragma unroll
    for (int i = 0; i < 4; ++i) {
        const int sr = (t >> 4) + i * 16;
        const int dc = (t & 15) * 4;
        const float4 v = *reinterpret_cast<const float4*>(
            &V[(size_t)(b * S + s0 + sr) * stride + col_off + u * HD + dv0 + dc]);
        const u16 hx = f2bf(v.x), hy = f2bf(v.y), hz = f2bf(v.z), hw = f2bf(v.w);
        th[sr][dc + 0] = hx; tl[sr][dc + 0] = f2bf(v.x - bf2f(hx));
        th[sr][dc + 1] = hy; tl[sr][dc + 1] = f2bf(v.y - bf2f(hy));
        th[sr][dc + 2] = hz; tl[sr][dc + 2] = f2bf(v.z - bf2f(hz));
        th[sr][dc + 3] = hw; tl[sr][dc + 3] = f2bf(v.w - bf2f(hw));
    }
    __syncthreads();
#pragma unroll
    for (int i = 0; i < 4; ++i) {
        const int dr = (t >> 4) + i * 16;
        const int sc = (t & 15) * 4;
        ushort4 oh, ol;
        oh.x = th[sc + 0][dr]; ol.x = tl[sc + 0][dr];
        oh.y = th[sc + 1][dr]; ol.y = tl[sc + 1][dr];
        oh.z = th[sc + 2][dr]; ol.z = tl[sc + 2][dr];
        oh.w = th[sc + 3][dr]; ol.w = tl[sc + 3][dr];
        const size_t o = ((size_t)(b * NKV + u) * HD + dv0 + dr) * S + s0 + sc;
        *reinterpret_cast<ushort4*>(&Yh[o]) = oh;
        *reinterpret_cast<ushort4*>(&Yl[o]) = ol;
    }
}

// ---------------------------------------------------------------------------
// Flash attention, double-bf16 hi/lo MFMA, fp32 online softmax.
// BARRIER-FREE: K and V^T fragments are loaded directly from global (L2/L3
// resident); no K/V LDS staging, no __syncthreads in the k-loop. LDS is used
// only for the per-wave P redistribution (D-layout -> A-layout), which is
// wave-internal (lgkmcnt wait, no barrier). Fragment lane mappings identical
// to the validated round-3/4 kernel.
// ---------------------------------------------------------------------------
constexpr int QTILE = 64, KT = 32;

__global__ __launch_bounds__(256)
void flash_mfma_kernel(const u16* __restrict__ Qh, const u16* __restrict__ Ql,
                       const u16* __restrict__ Kh, const u16* __restrict__ Kl,
                       const u16* __restrict__ Vh, const u16* __restrict__ Vl,
                       u16* __restrict__ Oh, u16* __restrict__ Ol)
{
    __shared__ alignas(16) u16 PHs[4 * 640];
    __shared__ alignas(16) u16 PLs[4 * 640];

    const int t  = threadIdx.x;
    const int w  = t >> 6;
    const int ln = t & 63;
    const int lg = ln >> 4;             // 0..3
    const int lc = ln & 15;             // 0..15

    const int qt = (int)gridDim.x - 1 - (int)blockIdx.x;   // heavy tiles first
    const int q0 = qt * QTILE;
    const int bh = blockIdx.y;
    const int b  = bh / NH, h = bh % NH, u = h / GRP;

    const size_t qbase = (size_t)(b * NH + h) * S * HD;
    const size_t kbase = (size_t)(b * NKV + u) * S * HD;
    const size_t vbase = (size_t)(b * NKV + u) * HD * S;

    const int qw0 = q0 + w * 16;        // this wave's first q row

    // ---- Q fragments straight from global: row qw0+lc, cols ks*32+lg*8 ----
    short8 qah[4], qal[4];
    {
        const size_t qr = qbase + (size_t)(qw0 + lc) * HD + lg * 8;
#pragma unroll
        for (int ks = 0; ks < 4; ++ks) {
            qah[ks] = *reinterpret_cast<const short8*>(&Qh[qr + ks * 32]);
            qal[ks] = *reinterpret_cast<const short8*>(&Ql[qr + ks * 32]);
        }
    }

    f32x4 o[8];
#pragma unroll
    for (int i = 0; i < 8; ++i) o[i] = (f32x4){0.f, 0.f, 0.f, 0.f};
    float m_run[4] = {-1e30f, -1e30f, -1e30f, -1e30f};
    float l_run[4] = {0.f, 0.f, 0.f, 0.f};

    u16* PwH = PHs + w * 640;
    u16* PwL = PLs + w * 640;

    const int nkt = qw0 / KT + 1;       // per-wave causal trip count

    for (int kt = 0; kt < nkt; ++kt) {
        const int k0 = kt * KT;

        // ---- K fragments direct from global (rows k0+lc / k0+16+lc) ----
        short8 kb0h[4], kb0l[4], kb1h[4], kb1l[4];
        {
            const size_t kr0 = kbase + (size_t)(k0 + lc) * HD + lg * 8;
            const size_t kr1 = kr0 + (size_t)16 * HD;
#pragma unroll
            for (int ks = 0; ks < 4; ++ks) {
                kb0h[ks] = *reinterpret_cast<const short8*>(&Kh[kr0 + ks * 32]);
                kb0l[ks] = *reinterpret_cast<const short8*>(&Kl[kr0 + ks * 32]);
                kb1h[ks] = *reinterpret_cast<const short8*>(&Kh[kr1 + ks * 32]);
                kb1l[ks] = *reinterpret_cast<const short8*>(&Kl[kr1 + ks * 32]);
            }
        }

        // ---- S = Q.K^T ----
        f32x4 a0 = {0.f, 0.f, 0.f, 0.f}, a1 = {0.f, 0.f, 0.f, 0.f};
        __builtin_amdgcn_s_setprio(1);
#pragma unroll
        for (int ks = 0; ks < 4; ++ks) {
            a0 = __builtin_amdgcn_mfma_f32_16x16x32_bf16(qal[ks], kb0h[ks], a0, 0, 0, 0);
            a0 = __builtin_amdgcn_mfma_f32_16x16x32_bf16(qah[ks], kb0l[ks], a0, 0, 0, 0);
            a0 = __builtin_amdgcn_mfma_f32_16x16x32_bf16(qah[ks], kb0h[ks], a0, 0, 0, 0);
            a1 = __builtin_amdgcn_mfma_f32_16x16x32_bf16(qal[ks], kb1h[ks], a1, 0, 0, 0);
            a1 = __builtin_amdgcn_mfma_f32_16x16x32_bf16(qah[ks], kb1l[ks], a1, 0, 0, 0);
            a1 = __builtin_amdgcn_mfma_f32_16x16x32_bf16(qah[ks], kb1h[ks], a1, 0, 0, 0);
        }
        __builtin_amdgcn_s_setprio(0);

        // ---- V^T fragments issued now; consumed after softmax ----
        short8 vbh[8], vbl[8];
#pragma unroll
        for (int nt = 0; nt < 8; ++nt) {
            const size_t vo = vbase + (size_t)(nt * 16 + lc) * S + k0 + lg * 8;
            vbh[nt] = *reinterpret_cast<const short8*>(&Vh[vo]);
            vbl[nt] = *reinterpret_cast<const short8*>(&Vl[vo]);
        }

        // ---- online softmax (rows m = lg*4+r) ----
        const bool need_mask = (k0 + KT - 1 > qw0);
#pragma unroll
        for (int r = 0; r < 4; ++r) {
            float s0 = a0[r], s1 = a1[r];
            const int qg = qw0 + lg * 4 + r;
            if (need_mask) {
                if (k0 + lc > qg)      s0 = -1e30f;
                if (k0 + 16 + lc > qg) s1 = -1e30f;
            }
            float mx = fmaxf(s0, s1);
            mx = fmaxf(mx, __shfl_xor(mx, 1, 64));
            mx = fmaxf(mx, __shfl_xor(mx, 2, 64));
            mx = fmaxf(mx, __shfl_xor(mx, 4, 64));
            mx = fmaxf(mx, __shfl_xor(mx, 8, 64));
            const float mn  = fmaxf(m_run[r], mx);
            const float rsc = __expf(m_run[r] - mn);
            const float p0  = __expf(s0 - mn);
            const float p1  = __expf(s1 - mn);
            float rs = p0 + p1;
            rs += __shfl_xor(rs, 1, 64);
            rs += __shfl_xor(rs, 2, 64);
            rs += __shfl_xor(rs, 4, 64);
            rs += __shfl_xor(rs, 8, 64);
            l_run[r] = l_run[r] * rsc + rs;
            m_run[r] = mn;
#pragma unroll
            for (int nt = 0; nt < 8; ++nt) o[nt][r] *= rsc;
            const u16 p0h = f2bf(p0);
            const u16 p1h = f2bf(p1);
            const int row = (lg * 4 + r) * 40;
            PwH[row + lc]      = p0h;
            PwH[row + 16 + lc] = p1h;
            PwL[row + lc]      = f2bf(p0 - bf2f(p0h));
            PwL[row + 16 + lc] = f2bf(p1 - bf2f(p1h));
        }
        asm volatile("s_waitcnt lgkmcnt(0)" ::: "memory");

        // ---- O += P.V ----
        const short8 pah = *reinterpret_cast<const short8*>(&PwH[lc * 40 + lg * 8]);
        const short8 pal = *reinterpret_cast<const short8*>(&PwL[lc * 40 + lg * 8]);
        __builtin_amdgcn_s_setprio(1);
#pragma unroll
        for (int nt = 0; nt < 8; ++nt) {
            o[nt] = __builtin_amdgcn_mfma_f32_16x16x32_bf16(pal, vbh[nt], o[nt], 0, 0, 0);
            o[nt] = __builtin_amdgcn_mfma_f32_16x16x32_bf16(pah, vbl[nt], o[nt], 0, 0, 0);
            o[nt] = __builtin_amdgcn_mfma_f32_16x16x32_bf16(pah, vbh[nt], o[nt], 0, 0, 0);
        }
        __builtin_amdgcn_s_setprio(0);
    }

    float invl[4];
#pragma unroll
    for (int r = 0; r < 4; ++r) invl[r] = 1.f / l_run[r];
#pragma unroll
    for (int nt = 0; nt < 8; ++nt) {
#pragma unroll
        for (int r = 0; r < 4; ++r) {
            const float v = o[nt][r] * invl[r];
            const size_t off =
                (size_t)(b * S + qw0 + lg * 4 + r) * (NH * HD) + h * HD + nt * 16 + lc;
            const u16 hv = f2bf(v);
            Oh[off] = hv;
            Ol[off] = f2bf(v - bf2f(hv));
        }
    }
}

} // anonymous namespace

// ---------------------------------------------------------------------------
// Workspace layout identical to round 4 (120 MiB with aliasing).
// ---------------------------------------------------------------------------
extern "C" void kernel_launch(void* const* d_in, const int* in_sizes, int n_in,
                              void* d_out, int out_size, void* d_ws, size_t ws_size,
                              hipStream_t stream)
{
    const float* hidden = (const float*)d_in[0];
    const float* Wq = (const float*)d_in[2];
    const float* Wk = (const float*)d_in[3];
    const float* Wv = (const float*)d_in[4];
    const float* Wo = (const float*)d_in[5];
    float* out = (float*)d_out;

    char* wsb = (char*)d_ws;
    u16*   hid_hi  = (u16*)(wsb);
    u16*   hid_lo  = (u16*)(wsb + 16777216);
    float* qkv_f   = (float*)(wsb + 33554432);
    u16*   k_hi    = (u16*)(wsb + 83886080);
    u16*   k_lo    = (u16*)(wsb + 88080384);
    u16*   v_hi    = (u16*)(wsb + 92274688);
    u16*   v_lo    = (u16*)(wsb + 96468992);
    u16*   wT_hi   = (u16*)(wsb + 100663296);
    u16*   wT_lo   = (u16*)(wsb + 113246208);
    // aliases
    u16* q_hi    = hid_hi;                     // hid dead after GEMM1
    u16* q_lo    = hid_lo;
    u16* attn_hi = (u16*)(wsb + 33554432);     // qkv_f dead after rope/vcast
    u16* attn_lo = (u16*)(wsb + 50331648);
    u16* woT_hi  = wT_hi;                      // WqkvT dead after GEMM1
    u16* woT_lo  = wT_lo;

    const dim3 blk(256);

    split_cast_kernel<<<dim3(8192), blk, 0, stream>>>(hidden, hid_hi, hid_lo, 2097152);
    wcast_t_kernel<<<dim3(32, 32), blk, 0, stream>>>(Wq, wT_hi, wT_lo, 2048, 0);
    wcast_t_kernel<<<dim3(8, 32),  blk, 0, stream>>>(Wk, wT_hi, wT_lo, 512, 2048);
    wcast_t_kernel<<<dim3(8, 32),  blk, 0, stream>>>(Wv, wT_hi, wT_lo, 512, 2560);
    hgemm_hilo_kernel<<<dim3(24, 32), blk, 0, stream>>>(
        hid_hi, hid_lo, wT_hi, wT_lo, qkv_f, 4096, 3072, 2048);
    wcast_t_kernel<<<dim3(32, 32), blk, 0, stream>>>(Wo, woT_hi, woT_lo, 2048, 0);
    const int qpairs = 4096 * NH * 64;
    const int kpairs = 4096 * NKV * 64;
    rope_cast_kernel<<<dim3(qpairs / 256), blk, 0, stream>>>(
        qkv_f, 3072, 0, q_hi, q_lo, NH, qpairs, 0.08838834764831845f);
    rope_cast_kernel<<<dim3(kpairs / 256), blk, 0, stream>>>(
        qkv_f, 3072, 2048, k_hi, k_lo, NKV, kpairs, 1.0f);
    vcast_kernel<<<dim3(32, 2, 8), blk, 0, stream>>>(
        qkv_f, 3072, 2560, v_hi, v_lo);
    flash_mfma_kernel<<<dim3(S / QTILE, B * NH), blk, 0, stream>>>(
        q_hi, q_lo, k_hi, k_lo, v_hi, v_lo, attn_hi, attn_lo);
    hgemm_hilo_kernel<<<dim3(16, 32), blk, 0, stream>>>(
        attn_hi, attn_lo, woT_hi, woT_lo, out, 4096, 2048, 2048);
}

// Round 6
// 797.608 us; speedup vs baseline: 1.6666x; 1.6666x over previous
//
#include <hip/hip_runtime.h>
#include <math.h>

namespace {

constexpr int B   = 2;
constexpr int S   = 2048;
constexpr int D   = 2048;
constexpr int NH  = 16;
constexpr int NKV = 4;
constexpr int HD  = 128;
constexpr int GRP = NH / NKV;   // 4

typedef __attribute__((ext_vector_type(8))) short  short8;
typedef __attribute__((ext_vector_type(4))) float  f32x4;
typedef unsigned short u16;

__device__ inline u16 f2bf(float f) {
    unsigned u = __float_as_uint(f);
    u = (u + 0x7FFFu + ((u >> 16) & 1u)) >> 16;   // RNE
    return (u16)u;
}
__device__ inline float bf2f(u16 h) {
    return __uint_as_float((unsigned)h << 16);
}

// async global->LDS, 16B per lane; LDS dest = wave-uniform base + lane*16.
__device__ __forceinline__ void gload_lds16(const void* g, void* l) {
    __builtin_amdgcn_global_load_lds(
        (const __attribute__((address_space(1))) unsigned int*)g,
        (__attribute__((address_space(3))) unsigned int*)l, 16, 0, 0);
}

// ---------------------------------------------------------------------------
// split-cast fp32 -> (bf16 hi, bf16 lo), elementwise, float4-vectorized.
// ---------------------------------------------------------------------------
__global__ __launch_bounds__(256)
void split_cast_kernel(const float* __restrict__ X, u16* __restrict__ H,
                       u16* __restrict__ L, int n4)
{
    const int idx = blockIdx.x * 256 + threadIdx.x;
    if (idx >= n4) return;
    const float4 v = reinterpret_cast<const float4*>(X)[idx];
    ushort4 h, l;
    h.x = f2bf(v.x); l.x = f2bf(v.x - bf2f(h.x));
    h.y = f2bf(v.y); l.y = f2bf(v.y - bf2f(h.y));
    h.z = f2bf(v.z); l.z = f2bf(v.z - bf2f(h.z));
    h.w = f2bf(v.w); l.w = f2bf(v.w - bf2f(h.w));
    reinterpret_cast<ushort4*>(H)[idx] = h;
    reinterpret_cast<ushort4*>(L)[idx] = l;
}

// ---------------------------------------------------------------------------
// Weight transpose-cast: W [K=2048][Nw] fp32 -> T hi/lo [n_off+Nw][2048] bf16.
// ---------------------------------------------------------------------------
__global__ __launch_bounds__(256)
void wcast_t_kernel(const float* __restrict__ W, u16* __restrict__ Th,
                    u16* __restrict__ Tl, int Nw, int n_off)
{
    __shared__ u16 th[64][68];
    __shared__ u16 tl[64][68];
    const int t  = threadIdx.x;
    const int n0 = blockIdx.x * 64;
    const int k0 = blockIdx.y * 64;

#pragma unroll
    for (int i = 0; i < 4; ++i) {
        const int kr = (t >> 4) + i * 16;
        const int nc = (t & 15) * 4;
        const float4 v = *reinterpret_cast<const float4*>(
            &W[(size_t)(k0 + kr) * Nw + n0 + nc]);
        const u16 hx = f2bf(v.x), hy = f2bf(v.y), hz = f2bf(v.z), hw = f2bf(v.w);
        th[kr][nc + 0] = hx; tl[kr][nc + 0] = f2bf(v.x - bf2f(hx));
        th[kr][nc + 1] = hy; tl[kr][nc + 1] = f2bf(v.y - bf2f(hy));
        th[kr][nc + 2] = hz; tl[kr][nc + 2] = f2bf(v.z - bf2f(hz));
        th[kr][nc + 3] = hw; tl[kr][nc + 3] = f2bf(v.w - bf2f(hw));
    }
    __syncthreads();
#pragma unroll
    for (int i = 0; i < 4; ++i) {
        const int nr = (t >> 4) + i * 16;
        const int kc = (t & 15) * 4;
        ushort4 oh, ol;
        oh.x = th[kc + 0][nr]; ol.x = tl[kc + 0][nr];
        oh.y = th[kc + 1][nr]; ol.y = tl[kc + 1][nr];
        oh.z = th[kc + 2][nr]; ol.z = tl[kc + 2][nr];
        oh.w = th[kc + 3][nr]; ol.w = tl[kc + 3][nr];
        const size_t o = (size_t)(n_off + n0 + nr) * 2048 + k0 + kc;
        *reinterpret_cast<ushort4*>(&Th[o]) = oh;
        *reinterpret_cast<ushort4*>(&Tl[o]) = ol;
    }
}

// ---------------------------------------------------------------------------
// hi/lo double-bf16 MFMA GEMM: C = A.B^T, fp32 out. (unchanged from round 4)
// ---------------------------------------------------------------------------
__global__ __launch_bounds__(256)
void hgemm_hilo_kernel(const u16* __restrict__ Ah, const u16* __restrict__ Al,
                       const u16* __restrict__ Bth, const u16* __restrict__ Btl,
                       float* __restrict__ C, int M, int N, int K)
{
    __shared__ alignas(16) u16 AsH[4096];
    __shared__ alignas(16) u16 AsL[4096];
    __shared__ alignas(16) u16 BsH[4096];
    __shared__ alignas(16) u16 BsL[4096];

    const int t  = threadIdx.x;
    const int w  = t >> 6;
    const int l  = t & 63;
    const int lc = l & 15;
    const int kg = l >> 4;
    const int wr = w >> 1, wc = w & 1;

    const int m0 = blockIdx.y * 128;
    const int n0 = blockIdx.x * 128;

    const int srow = l >> 2;
    const int sblk = l & 3;

    f32x4 acc[4][4];
#pragma unroll
    for (int i = 0; i < 4; ++i)
#pragma unroll
        for (int j = 0; j < 4; ++j) acc[i][j] = (f32x4){0.f, 0.f, 0.f, 0.f};

    for (int k0 = 0; k0 < K; k0 += 32) {
#pragma unroll
        for (int i = 0; i < 2; ++i) {
            const int c   = i * 4 + w;
            const int row = c * 16 + srow;
            const int swb = sblk ^ ((row >> 1) & 3);
            const size_t ga = (size_t)(m0 + row) * K + k0 + swb * 8;
            const size_t gb = (size_t)(n0 + row) * K + k0 + swb * 8;
            gload_lds16(Ah  + ga, AsH + c * 512);
            gload_lds16(Al  + ga, AsL + c * 512);
            gload_lds16(Bth + gb, BsH + c * 512);
            gload_lds16(Btl + gb, BsL + c * 512);
        }
        __syncthreads();

        short8 fah[4], fal[4], fbh[4], fbl[4];
#pragma unroll
        for (int i = 0; i < 4; ++i) {
            const int ra = wr * 64 + i * 16 + lc;
            const int oa = ra * 32 + ((kg ^ ((ra >> 1) & 3)) * 8);
            fah[i] = *reinterpret_cast<const short8*>(&AsH[oa]);
            fal[i] = *reinterpret_cast<const short8*>(&AsL[oa]);
            const int rb = wc * 64 + i * 16 + lc;
            const int ob = rb * 32 + ((kg ^ ((rb >> 1) & 3)) * 8);
            fbh[i] = *reinterpret_cast<const short8*>(&BsH[ob]);
            fbl[i] = *reinterpret_cast<const short8*>(&BsL[ob]);
        }
#pragma unroll
        for (int i = 0; i < 4; ++i)
#pragma unroll
            for (int j = 0; j < 4; ++j) {
                acc[i][j] = __builtin_amdgcn_mfma_f32_16x16x32_bf16(
                    fal[i], fbh[j], acc[i][j], 0, 0, 0);
                acc[i][j] = __builtin_amdgcn_mfma_f32_16x16x32_bf16(
                    fah[i], fbl[j], acc[i][j], 0, 0, 0);
                acc[i][j] = __builtin_amdgcn_mfma_f32_16x16x32_bf16(
                    fah[i], fbh[j], acc[i][j], 0, 0, 0);
            }
        __syncthreads();
    }

#pragma unroll
    for (int i = 0; i < 4; ++i)
#pragma unroll
        for (int j = 0; j < 4; ++j)
#pragma unroll
            for (int r = 0; r < 4; ++r) {
                const int m = m0 + wr * 64 + i * 16 + kg * 4 + r;
                const int n = n0 + wc * 64 + j * 16 + lc;
                C[(size_t)m * N + n] = acc[i][j][r];
            }
}

// ---------------------------------------------------------------------------
// RoPE + split-cast fp32 -> bf16 hi/lo, head-major [B][nh][S][HD].
// ---------------------------------------------------------------------------
__global__ __launch_bounds__(256)
void rope_cast_kernel(const float* __restrict__ X, int stride, int col_off,
                      u16* __restrict__ Yh, u16* __restrict__ Yl,
                      int n_heads, int total_pairs, float scale)
{
    const int idx = blockIdx.x * 256 + threadIdx.x;
    if (idx >= total_pairs) return;
    const int i    = idx & 63;
    const int rest = idx >> 6;
    const int head = rest % n_heads;
    const int row  = rest / n_heads;
    const int s    = row & (S - 1);
    const int b    = row >> 11;

    const float inv = expf(-9.2103403719761836f * (float)i * (1.0f / 64.0f));
    float sn, cs;
    sincosf((float)s * inv, &sn, &cs);

    const float* src = X + (size_t)row * stride + col_off + head * HD + i;
    const float x1 = src[0], x2 = src[64];
    const float y1 = (x1 * cs - x2 * sn) * scale;
    const float y2 = (x2 * cs + x1 * sn) * scale;

    const u16 h1 = f2bf(y1), h2 = f2bf(y2);
    const size_t o = ((size_t)(b * n_heads + head) * S + s) * HD + i;
    Yh[o] = h1;  Yh[o + 64] = h2;
    Yl[o]      = f2bf(y1 - bf2f(h1));
    Yl[o + 64] = f2bf(y2 - bf2f(h2));
}

// ---------------------------------------------------------------------------
// V: fp32 (from fused QKV buffer) -> bf16 hi/lo transposed [B][NKV][HD][S].
// ---------------------------------------------------------------------------
__global__ __launch_bounds__(256)
void vcast_kernel(const float* __restrict__ V, int stride, int col_off,
                  u16* __restrict__ Yh, u16* __restrict__ Yl)
{
    __shared__ u16 th[64][68];
    __shared__ u16 tl[64][68];
    const int t  = threadIdx.x;
    const int s0 = blockIdx.x * 64, dv0 = blockIdx.y * 64;
    const int b  = blockIdx.z >> 2, u = blockIdx.z & 3;

#pragma unroll
    for (int i = 0; i < 4; ++i) {
        const int sr = (t >> 4) + i * 16;
        const int dc = (t & 15) * 4;
        const float4 v = *reinterpret_cast<const float4*>(
            &V[(size_t)(b * S + s0 + sr) * stride + col_off + u * HD + dv0 + dc]);
        const u16 hx = f2bf(v.x), hy = f2bf(v.y), hz = f2bf(v.z), hw = f2bf(v.w);
        th[sr][dc + 0] = hx; tl[sr][dc + 0] = f2bf(v.x - bf2f(hx));
        th[sr][dc + 1] = hy; tl[sr][dc + 1] = f2bf(v.y - bf2f(hy));
        th[sr][dc + 2] = hz; tl[sr][dc + 2] = f2bf(v.z - bf2f(hz));
        th[sr][dc + 3] = hw; tl[sr][dc + 3] = f2bf(v.w - bf2f(hw));
    }
    __syncthreads();
#pragma unroll
    for (int i = 0; i < 4; ++i) {
        const int dr = (t >> 4) + i * 16;
        const int sc = (t & 15) * 4;
        ushort4 oh, ol;
        oh.x = th[sc + 0][dr]; ol.x = tl[sc + 0][dr];
        oh.y = th[sc + 1][dr]; ol.y = tl[sc + 1][dr];
        oh.z = th[sc + 2][dr]; ol.z = tl[sc + 2][dr];
        oh.w = th[sc + 3][dr]; ol.w = tl[sc + 3][dr];
        const size_t o = ((size_t)(b * NKV + u) * HD + dv0 + dr) * S + s0 + sc;
        *reinterpret_cast<ushort4*>(&Yh[o]) = oh;
        *reinterpret_cast<ushort4*>(&Yl[o]) = ol;
    }
}

// ---------------------------------------------------------------------------
// Flash attention, double-bf16 hi/lo MFMA, fp32 online softmax.
// Round-4 LDS-staged structure + (a) T14 async-STAGE split: next tile's
// global loads issued right after the first barrier, LDS-written at the top
// of the next iteration; (b) ILP-interleaved shfl reductions (4 independent
// row chains per step); (c) wave-uniform defer-max (THR=8, hi/lo P bounds
// the error); (d) per-wave causal skip of fully-masked tiles.
// ---------------------------------------------------------------------------
constexpr int QTILE = 64, KT = 32;

__global__ __launch_bounds__(256)
void flash_mfma_kernel(const u16* __restrict__ Qh, const u16* __restrict__ Ql,
                       const u16* __restrict__ Kh, const u16* __restrict__ Kl,
                       const u16* __restrict__ Vh, const u16* __restrict__ Vl,
                       u16* __restrict__ Oh, u16* __restrict__ Ol)
{
    __shared__ alignas(16) u16 smem[23552];
    u16* KsH = smem;
    u16* KsL = smem + 4096;
    u16* VtH = smem + 8192;
    u16* VtL = smem + 13312;
    u16* PH  = smem + 18432;
    u16* PL  = smem + 20992;

    const int t  = threadIdx.x;
    const int w  = t >> 6;
    const int ln = t & 63;
    const int lg = ln >> 4;             // 0..3
    const int lc = ln & 15;             // 0..15

    const int qt = (int)gridDim.x - 1 - (int)blockIdx.x;   // heavy tiles first
    const int q0 = qt * QTILE;
    const int bh = blockIdx.y;
    const int b  = bh / NH, h = bh % NH, u = h / GRP;

    const size_t qbase = (size_t)(b * NH + h) * S * HD;
    const size_t kbase = (size_t)(b * NKV + u) * S * HD;
    const size_t vbase = (size_t)(b * NKV + u) * HD * S;

    // ---- stage Q hi/lo tiles (swizzled), pull per-wave fragments ----
    {
        u16* QsH = smem;
        u16* QsL = smem + 8192;
#pragma unroll
        for (int i = 0; i < 4; ++i) {
            const int r = (t >> 4) + i * 16;
            const int blk = t & 15;
            const size_t src = qbase + (size_t)(q0 + r) * HD + blk * 8;
            const int dst = r * 128 + ((blk ^ (r & 7)) * 8);
            *reinterpret_cast<short8*>(&QsH[dst]) =
                *reinterpret_cast<const short8*>(&Qh[src]);
            *reinterpret_cast<short8*>(&QsL[dst]) =
                *reinterpret_cast<const short8*>(&Ql[src]);
        }
        __syncthreads();
    }
    short8 qah[4], qal[4];
#pragma unroll
    for (int ks = 0; ks < 4; ++ks) {
        const int qr = w * 16 + lc;
        const int off = qr * 128 + (((ks * 4 + lg) ^ (qr & 7)) * 8);
        qah[ks] = *reinterpret_cast<const short8*>(&smem[off]);
        qal[ks] = *reinterpret_cast<const short8*>(&smem[8192 + off]);
    }
    __syncthreads();

    f32x4 o[8];
#pragma unroll
    for (int i = 0; i < 8; ++i) o[i] = (f32x4){0.f, 0.f, 0.f, 0.f};
    float m_run[4] = {-1e30f, -1e30f, -1e30f, -1e30f};
    float l_run[4] = {0.f, 0.f, 0.f, 0.f};

    u16* PwH = PH + w * 640;
    u16* PwL = PL + w * 640;
    const int qw0 = q0 + w * 16;
    const int nkt = q0 / KT + 2;        // block-uniform trip count

    // staging thread roles + precomputed LDS dests (swizzle: 16 ≡ 0 mod 8)
    const int sr_k = t >> 4;            // 0..15
    const int sb_k = t & 15;
    const int sr_v = t >> 2;            // 0..63
    const int sb_v = t & 3;
    const int dKsw = (sb_k ^ (sr_k & 7)) * 8;
    const int dK0  = sr_k * 128 + dKsw;
    const int dK1  = (sr_k + 16) * 128 + dKsw;
    const int dV0  = sr_v * 40 + sb_v * 8;
    const int dV1  = (sr_v + 64) * 40 + sb_v * 8;

    short8 stg[8];
#define LOADTILE(K0)                                                          \
    {                                                                         \
        const size_t ksrc = kbase + (size_t)((K0) + sr_k) * HD + sb_k * 8;    \
        stg[0] = *reinterpret_cast<const short8*>(&Kh[ksrc]);                 \
        stg[1] = *reinterpret_cast<const short8*>(&Kh[ksrc + 16 * HD]);       \
        stg[2] = *reinterpret_cast<const short8*>(&Kl[ksrc]);                 \
        stg[3] = *reinterpret_cast<const short8*>(&Kl[ksrc + 16 * HD]);       \
        const size_t vsrc = vbase + (size_t)sr_v * S + (K0) + sb_v * 8;       \
        stg[4] = *reinterpret_cast<const short8*>(&Vh[vsrc]);                 \
        stg[5] = *reinterpret_cast<const short8*>(&Vh[vsrc + (size_t)64 * S]);\
        stg[6] = *reinterpret_cast<const short8*>(&Vl[vsrc]);                 \
        stg[7] = *reinterpret_cast<const short8*>(&Vl[vsrc + (size_t)64 * S]);\
    }

    LOADTILE(0);

    for (int kt = 0; kt < nkt; ++kt) {
        const int k0 = kt * KT;
        // write prefetched tile to LDS (consumers of the previous tile are
        // past the loop-end barrier)
        *reinterpret_cast<short8*>(&KsH[dK0]) = stg[0];
        *reinterpret_cast<short8*>(&KsH[dK1]) = stg[1];
        *reinterpret_cast<short8*>(&KsL[dK0]) = stg[2];
        *reinterpret_cast<short8*>(&KsL[dK1]) = stg[3];
        *reinterpret_cast<short8*>(&VtH[dV0]) = stg[4];
        *reinterpret_cast<short8*>(&VtH[dV1]) = stg[5];
        *reinterpret_cast<short8*>(&VtL[dV0]) = stg[6];
        *reinterpret_cast<short8*>(&VtL[dV1]) = stg[7];
        __syncthreads();

        // T14: issue next tile's global loads now; they fly under compute
        if (kt + 1 < nkt) LOADTILE(k0 + KT);

        if (k0 <= qw0 + 15) {           // wave-level causal skip
            // ---- S = Q.K^T ----
            f32x4 a0 = {0.f, 0.f, 0.f, 0.f}, a1 = {0.f, 0.f, 0.f, 0.f};
            __builtin_amdgcn_s_setprio(1);
#pragma unroll
            for (int ks = 0; ks < 4; ++ks) {
                const int r0 = lc, r1 = 16 + lc;
                const int o0b = r0 * 128 + (((ks * 4 + lg) ^ (r0 & 7)) * 8);
                const int o1b = r1 * 128 + (((ks * 4 + lg) ^ (r1 & 7)) * 8);
                const short8 kb0h = *reinterpret_cast<const short8*>(&KsH[o0b]);
                const short8 kb0l = *reinterpret_cast<const short8*>(&KsL[o0b]);
                const short8 kb1h = *reinterpret_cast<const short8*>(&KsH[o1b]);
                const short8 kb1l = *reinterpret_cast<const short8*>(&KsL[o1b]);
                a0 = __builtin_amdgcn_mfma_f32_16x16x32_bf16(qal[ks], kb0h, a0, 0, 0, 0);
                a0 = __builtin_amdgcn_mfma_f32_16x16x32_bf16(qah[ks], kb0l, a0, 0, 0, 0);
                a0 = __builtin_amdgcn_mfma_f32_16x16x32_bf16(qah[ks], kb0h, a0, 0, 0, 0);
                a1 = __builtin_amdgcn_mfma_f32_16x16x32_bf16(qal[ks], kb1h, a1, 0, 0, 0);
                a1 = __builtin_amdgcn_mfma_f32_16x16x32_bf16(qah[ks], kb1l, a1, 0, 0, 0);
                a1 = __builtin_amdgcn_mfma_f32_16x16x32_bf16(qah[ks], kb1h, a1, 0, 0, 0);
            }
            __builtin_amdgcn_s_setprio(0);

            // ---- online softmax: mask + per-lane max ----
            float s0v[4], s1v[4], mx[4];
            const bool need_mask = (k0 + KT - 1 > qw0);
#pragma unroll
            for (int r = 0; r < 4; ++r) {
                float s0 = a0[r], s1 = a1[r];
                const int qg = qw0 + lg * 4 + r;
                if (need_mask) {
                    if (k0 + lc > qg)      s0 = -1e30f;
                    if (k0 + 16 + lc > qg) s1 = -1e30f;
                }
                s0v[r] = s0; s1v[r] = s1;
                mx[r] = fmaxf(s0, s1);
            }
            // ILP: 4 independent reduction chains per step
#pragma unroll
            for (int off = 1; off < 16; off <<= 1)
#pragma unroll
                for (int r = 0; r < 4; ++r)
                    mx[r] = fmaxf(mx[r], __shfl_xor(mx[r], off, 64));

            // wave-uniform defer-max (T13, THR=8)
            bool grow = false;
#pragma unroll
            for (int r = 0; r < 4; ++r) grow = grow || (mx[r] > m_run[r] + 8.0f);
            const bool resc_needed = __any((int)grow);

            float mn[4], rsc[4];
#pragma unroll
            for (int r = 0; r < 4; ++r) {
                mn[r]  = resc_needed ? fmaxf(m_run[r], mx[r]) : m_run[r];
                rsc[r] = resc_needed ? __expf(m_run[r] - mn[r]) : 1.0f;
            }
            float p0[4], p1[4], rs[4];
#pragma unroll
            for (int r = 0; r < 4; ++r) {
                p0[r] = __expf(s0v[r] - mn[r]);
                p1[r] = __expf(s1v[r] - mn[r]);
                rs[r] = p0[r] + p1[r];
            }
#pragma unroll
            for (int off = 1; off < 16; off <<= 1)
#pragma unroll
                for (int r = 0; r < 4; ++r)
                    rs[r] += __shfl_xor(rs[r], off, 64);
#pragma unroll
            for (int r = 0; r < 4; ++r) {
                l_run[r] = l_run[r] * rsc[r] + rs[r];
                m_run[r] = mn[r];
            }
            if (resc_needed) {
#pragma unroll
                for (int nt = 0; nt < 8; ++nt)
#pragma unroll
                    for (int r = 0; r < 4; ++r) o[nt][r] *= rsc[r];
            }
#pragma unroll
            for (int r = 0; r < 4; ++r) {
                const u16 p0h = f2bf(p0[r]);
                const u16 p1h = f2bf(p1[r]);
                const int row = (lg * 4 + r) * 40;
                PwH[row + lc]      = p0h;
                PwH[row + 16 + lc] = p1h;
                PwL[row + lc]      = f2bf(p0[r] - bf2f(p0h));
                PwL[row + 16 + lc] = f2bf(p1[r] - bf2f(p1h));
            }
            asm volatile("s_waitcnt lgkmcnt(0)" ::: "memory");

            // ---- O += P.V ----
            const short8 pah = *reinterpret_cast<const short8*>(&PwH[lc * 40 + lg * 8]);
            const short8 pal = *reinterpret_cast<const short8*>(&PwL[lc * 40 + lg * 8]);
            __builtin_amdgcn_s_setprio(1);
#pragma unroll
            for (int nt = 0; nt < 8; ++nt) {
                const int dvo = (nt * 16 + lc) * 40 + lg * 8;
                const short8 vbh = *reinterpret_cast<const short8*>(&VtH[dvo]);
                const short8 vbl = *reinterpret_cast<const short8*>(&VtL[dvo]);
                o[nt] = __builtin_amdgcn_mfma_f32_16x16x32_bf16(pal, vbh, o[nt], 0, 0, 0);
                o[nt] = __builtin_amdgcn_mfma_f32_16x16x32_bf16(pah, vbl, o[nt], 0, 0, 0);
                o[nt] = __builtin_amdgcn_mfma_f32_16x16x32_bf16(pah, vbh, o[nt], 0, 0, 0);
            }
            __builtin_amdgcn_s_setprio(0);
        }
        __syncthreads();
    }
#undef LOADTILE

    float invl[4];
#pragma unroll
    for (int r = 0; r < 4; ++r) invl[r] = 1.f / l_run[r];
#pragma unroll
    for (int nt = 0; nt < 8; ++nt) {
#pragma unroll
        for (int r = 0; r < 4; ++r) {
            const float v = o[nt][r] * invl[r];
            const size_t off =
                (size_t)(b * S + qw0 + lg * 4 + r) * (NH * HD) + h * HD + nt * 16 + lc;
            const u16 hv = f2bf(v);
            Oh[off] = hv;
            Ol[off] = f2bf(v - bf2f(hv));
        }
    }
}

} // anonymous namespace

// ---------------------------------------------------------------------------
// Workspace layout identical to round 4 (120 MiB with aliasing).
// ---------------------------------------------------------------------------
extern "C" void kernel_launch(void* const* d_in, const int* in_sizes, int n_in,
                              void* d_out, int out_size, void* d_ws, size_t ws_size,
                              hipStream_t stream)
{
    const float* hidden = (const float*)d_in[0];
    const float* Wq = (const float*)d_in[2];
    const float* Wk = (const float*)d_in[3];
    const float* Wv = (const float*)d_in[4];
    const float* Wo = (const float*)d_in[5];
    float* out = (float*)d_out;

    char* wsb = (char*)d_ws;
    u16*   hid_hi  = (u16*)(wsb);
    u16*   hid_lo  = (u16*)(wsb + 16777216);
    float* qkv_f   = (float*)(wsb + 33554432);
    u16*   k_hi    = (u16*)(wsb + 83886080);
    u16*   k_lo    = (u16*)(wsb + 88080384);
    u16*   v_hi    = (u16*)(wsb + 92274688);
    u16*   v_lo    = (u16*)(wsb + 96468992);
    u16*   wT_hi   = (u16*)(wsb + 100663296);
    u16*   wT_lo   = (u16*)(wsb + 113246208);
    // aliases
    u16* q_hi    = hid_hi;                     // hid dead after GEMM1
    u16* q_lo    = hid_lo;
    u16* attn_hi = (u16*)(wsb + 33554432);     // qkv_f dead after rope/vcast
    u16* attn_lo = (u16*)(wsb + 50331648);
    u16* woT_hi  = wT_hi;                      // WqkvT dead after GEMM1
    u16* woT_lo  = wT_lo;

    const dim3 blk(256);

    split_cast_kernel<<<dim3(8192), blk, 0, stream>>>(hidden, hid_hi, hid_lo, 2097152);
    wcast_t_kernel<<<dim3(32, 32), blk, 0, stream>>>(Wq, wT_hi, wT_lo, 2048, 0);
    wcast_t_kernel<<<dim3(8, 32),  blk, 0, stream>>>(Wk, wT_hi, wT_lo, 512, 2048);
    wcast_t_kernel<<<dim3(8, 32),  blk, 0, stream>>>(Wv, wT_hi, wT_lo, 512, 2560);
    hgemm_hilo_kernel<<<dim3(24, 32), blk, 0, stream>>>(
        hid_hi, hid_lo, wT_hi, wT_lo, qkv_f, 4096, 3072, 2048);
    wcast_t_kernel<<<dim3(32, 32), blk, 0, stream>>>(Wo, woT_hi, woT_lo, 2048, 0);
    const int qpairs = 4096 * NH * 64;
    const int kpairs = 4096 * NKV * 64;
    rope_cast_kernel<<<dim3(qpairs / 256), blk, 0, stream>>>(
        qkv_f, 3072, 0, q_hi, q_lo, NH, qpairs, 0.08838834764831845f);
    rope_cast_kernel<<<dim3(kpairs / 256), blk, 0, stream>>>(
        qkv_f, 3072, 2048, k_hi, k_lo, NKV, kpairs, 1.0f);
    vcast_kernel<<<dim3(32, 2, 8), blk, 0, stream>>>(
        qkv_f, 3072, 2560, v_hi, v_lo);
    flash_mfma_kernel<<<dim3(S / QTILE, B * NH), blk, 0, stream>>>(
        q_hi, q_lo, k_hi, k_lo, v_hi, v_lo, attn_hi, attn_lo);
    hgemm_hilo_kernel<<<dim3(16, 32), blk, 0, stream>>>(
        attn_hi, attn_lo, woT_hi, woT_lo, out, 4096, 2048, 2048);
}

// Round 7
// 716.300 us; speedup vs baseline: 1.8558x; 1.1135x over previous
//
#include <hip/hip_runtime.h>
#include <math.h>

namespace {

constexpr int B   = 2;
constexpr int S   = 2048;
constexpr int D   = 2048;
constexpr int NH  = 16;
constexpr int NKV = 4;
constexpr int HD  = 128;
constexpr int GRP = NH / NKV;   // 4

typedef __attribute__((ext_vector_type(8))) short  short8;
typedef __attribute__((ext_vector_type(4))) float  f32x4;
typedef unsigned short u16;

__device__ inline u16 f2bf(float f) {
    unsigned u = __float_as_uint(f);
    u = (u + 0x7FFFu + ((u >> 16) & 1u)) >> 16;   // RNE
    return (u16)u;
}
__device__ inline float bf2f(u16 h) {
    return __uint_as_float((unsigned)h << 16);
}

// async global->LDS, 16B per lane; LDS dest = wave-uniform base + lane*16.
__device__ __forceinline__ void gload_lds16(const void* g, void* l) {
    __builtin_amdgcn_global_load_lds(
        (const __attribute__((address_space(1))) unsigned int*)g,
        (__attribute__((address_space(3))) unsigned int*)l, 16, 0, 0);
}

// ---------------------------------------------------------------------------
// split-cast fp32 -> (bf16 hi, bf16 lo), elementwise, float4-vectorized.
// ---------------------------------------------------------------------------
__global__ __launch_bounds__(256)
void split_cast_kernel(const float* __restrict__ X, u16* __restrict__ H,
                       u16* __restrict__ L, int n4)
{
    const int idx = blockIdx.x * 256 + threadIdx.x;
    if (idx >= n4) return;
    const float4 v = reinterpret_cast<const float4*>(X)[idx];
    ushort4 h, l;
    h.x = f2bf(v.x); l.x = f2bf(v.x - bf2f(h.x));
    h.y = f2bf(v.y); l.y = f2bf(v.y - bf2f(h.y));
    h.z = f2bf(v.z); l.z = f2bf(v.z - bf2f(h.z));
    h.w = f2bf(v.w); l.w = f2bf(v.w - bf2f(h.w));
    reinterpret_cast<ushort4*>(H)[idx] = h;
    reinterpret_cast<ushort4*>(L)[idx] = l;
}

// ---------------------------------------------------------------------------
// Weight transpose-cast: W [K=2048][Nw] fp32 -> T hi/lo [n_off+Nw][2048] bf16.
// ---------------------------------------------------------------------------
__global__ __launch_bounds__(256)
void wcast_t_kernel(const float* __restrict__ W, u16* __restrict__ Th,
                    u16* __restrict__ Tl, int Nw, int n_off)
{
    __shared__ u16 th[64][68];
    __shared__ u16 tl[64][68];
    const int t  = threadIdx.x;
    const int n0 = blockIdx.x * 64;
    const int k0 = blockIdx.y * 64;

#pragma unroll
    for (int i = 0; i < 4; ++i) {
        const int kr = (t >> 4) + i * 16;
        const int nc = (t & 15) * 4;
        const float4 v = *reinterpret_cast<const float4*>(
            &W[(size_t)(k0 + kr) * Nw + n0 + nc]);
        const u16 hx = f2bf(v.x), hy = f2bf(v.y), hz = f2bf(v.z), hw = f2bf(v.w);
        th[kr][nc + 0] = hx; tl[kr][nc + 0] = f2bf(v.x - bf2f(hx));
        th[kr][nc + 1] = hy; tl[kr][nc + 1] = f2bf(v.y - bf2f(hy));
        th[kr][nc + 2] = hz; tl[kr][nc + 2] = f2bf(v.z - bf2f(hz));
        th[kr][nc + 3] = hw; tl[kr][nc + 3] = f2bf(v.w - bf2f(hw));
    }
    __syncthreads();
#pragma unroll
    for (int i = 0; i < 4; ++i) {
        const int nr = (t >> 4) + i * 16;
        const int kc = (t & 15) * 4;
        ushort4 oh, ol;
        oh.x = th[kc + 0][nr]; ol.x = tl[kc + 0][nr];
        oh.y = th[kc + 1][nr]; ol.y = tl[kc + 1][nr];
        oh.z = th[kc + 2][nr]; ol.z = tl[kc + 2][nr];
        oh.w = th[kc + 3][nr]; ol.w = tl[kc + 3][nr];
        const size_t o = (size_t)(n_off + n0 + nr) * 2048 + k0 + kc;
        *reinterpret_cast<ushort4*>(&Th[o]) = oh;
        *reinterpret_cast<ushort4*>(&Tl[o]) = ol;
    }
}

// ---------------------------------------------------------------------------
// hi/lo double-bf16 MFMA GEMM: C = A.B^T, fp32 out. (unchanged)
// ---------------------------------------------------------------------------
__global__ __launch_bounds__(256)
void hgemm_hilo_kernel(const u16* __restrict__ Ah, const u16* __restrict__ Al,
                       const u16* __restrict__ Bth, const u16* __restrict__ Btl,
                       float* __restrict__ C, int M, int N, int K)
{
    __shared__ alignas(16) u16 AsH[4096];
    __shared__ alignas(16) u16 AsL[4096];
    __shared__ alignas(16) u16 BsH[4096];
    __shared__ alignas(16) u16 BsL[4096];

    const int t  = threadIdx.x;
    const int w  = t >> 6;
    const int l  = t & 63;
    const int lc = l & 15;
    const int kg = l >> 4;
    const int wr = w >> 1, wc = w & 1;

    const int m0 = blockIdx.y * 128;
    const int n0 = blockIdx.x * 128;

    const int srow = l >> 2;
    const int sblk = l & 3;

    f32x4 acc[4][4];
#pragma unroll
    for (int i = 0; i < 4; ++i)
#pragma unroll
        for (int j = 0; j < 4; ++j) acc[i][j] = (f32x4){0.f, 0.f, 0.f, 0.f};

    for (int k0 = 0; k0 < K; k0 += 32) {
#pragma unroll
        for (int i = 0; i < 2; ++i) {
            const int c   = i * 4 + w;
            const int row = c * 16 + srow;
            const int swb = sblk ^ ((row >> 1) & 3);
            const size_t ga = (size_t)(m0 + row) * K + k0 + swb * 8;
            const size_t gb = (size_t)(n0 + row) * K + k0 + swb * 8;
            gload_lds16(Ah  + ga, AsH + c * 512);
            gload_lds16(Al  + ga, AsL + c * 512);
            gload_lds16(Bth + gb, BsH + c * 512);
            gload_lds16(Btl + gb, BsL + c * 512);
        }
        __syncthreads();

        short8 fah[4], fal[4], fbh[4], fbl[4];
#pragma unroll
        for (int i = 0; i < 4; ++i) {
            const int ra = wr * 64 + i * 16 + lc;
            const int oa = ra * 32 + ((kg ^ ((ra >> 1) & 3)) * 8);
            fah[i] = *reinterpret_cast<const short8*>(&AsH[oa]);
            fal[i] = *reinterpret_cast<const short8*>(&AsL[oa]);
            const int rb = wc * 64 + i * 16 + lc;
            const int ob = rb * 32 + ((kg ^ ((rb >> 1) & 3)) * 8);
            fbh[i] = *reinterpret_cast<const short8*>(&BsH[ob]);
            fbl[i] = *reinterpret_cast<const short8*>(&BsL[ob]);
        }
#pragma unroll
        for (int i = 0; i < 4; ++i)
#pragma unroll
            for (int j = 0; j < 4; ++j) {
                acc[i][j] = __builtin_amdgcn_mfma_f32_16x16x32_bf16(
                    fal[i], fbh[j], acc[i][j], 0, 0, 0);
                acc[i][j] = __builtin_amdgcn_mfma_f32_16x16x32_bf16(
                    fah[i], fbl[j], acc[i][j], 0, 0, 0);
                acc[i][j] = __builtin_amdgcn_mfma_f32_16x16x32_bf16(
                    fah[i], fbh[j], acc[i][j], 0, 0, 0);
            }
        __syncthreads();
    }

#pragma unroll
    for (int i = 0; i < 4; ++i)
#pragma unroll
        for (int j = 0; j < 4; ++j)
#pragma unroll
            for (int r = 0; r < 4; ++r) {
                const int m = m0 + wr * 64 + i * 16 + kg * 4 + r;
                const int n = n0 + wc * 64 + j * 16 + lc;
                C[(size_t)m * N + n] = acc[i][j][r];
            }
}

// ---------------------------------------------------------------------------
// RoPE + split-cast fp32 -> bf16 hi/lo, head-major [B][nh][S][HD].
// ---------------------------------------------------------------------------
__global__ __launch_bounds__(256)
void rope_cast_kernel(const float* __restrict__ X, int stride, int col_off,
                      u16* __restrict__ Yh, u16* __restrict__ Yl,
                      int n_heads, int total_pairs, float scale)
{
    const int idx = blockIdx.x * 256 + threadIdx.x;
    if (idx >= total_pairs) return;
    const int i    = idx & 63;
    const int rest = idx >> 6;
    const int head = rest % n_heads;
    const int row  = rest / n_heads;
    const int s    = row & (S - 1);
    const int b    = row >> 11;

    const float inv = expf(-9.2103403719761836f * (float)i * (1.0f / 64.0f));
    float sn, cs;
    sincosf((float)s * inv, &sn, &cs);

    const float* src = X + (size_t)row * stride + col_off + head * HD + i;
    const float x1 = src[0], x2 = src[64];
    const float y1 = (x1 * cs - x2 * sn) * scale;
    const float y2 = (x2 * cs + x1 * sn) * scale;

    const u16 h1 = f2bf(y1), h2 = f2bf(y2);
    const size_t o = ((size_t)(b * n_heads + head) * S + s) * HD + i;
    Yh[o] = h1;  Yh[o + 64] = h2;
    Yl[o]      = f2bf(y1 - bf2f(h1));
    Yl[o + 64] = f2bf(y2 - bf2f(h2));
}

// ---------------------------------------------------------------------------
// V: fp32 (from fused QKV buffer) -> bf16 hi/lo transposed [B][NKV][HD][S].
// ---------------------------------------------------------------------------
__global__ __launch_bounds__(256)
void vcast_kernel(const float* __restrict__ V, int stride, int col_off,
                  u16* __restrict__ Yh, u16* __restrict__ Yl)
{
    __shared__ u16 th[64][68];
    __shared__ u16 tl[64][68];
    const int t  = threadIdx.x;
    const int s0 = blockIdx.x * 64, dv0 = blockIdx.y * 64;
    const int b  = blockIdx.z >> 2, u = blockIdx.z & 3;

#pragma unroll
    for (int i = 0; i < 4; ++i) {
        const int sr = (t >> 4) + i * 16;
        const int dc = (t & 15) * 4;
        const float4 v = *reinterpret_cast<const float4*>(
            &V[(size_t)(b * S + s0 + sr) * stride + col_off + u * HD + dv0 + dc]);
        const u16 hx = f2bf(v.x), hy = f2bf(v.y), hz = f2bf(v.z), hw = f2bf(v.w);
        th[sr][dc + 0] = hx; tl[sr][dc + 0] = f2bf(v.x - bf2f(hx));
        th[sr][dc + 1] = hy; tl[sr][dc + 1] = f2bf(v.y - bf2f(hy));
        th[sr][dc + 2] = hz; tl[sr][dc + 2] = f2bf(v.z - bf2f(hz));
        th[sr][dc + 3] = hw; tl[sr][dc + 3] = f2bf(v.w - bf2f(hw));
    }
    __syncthreads();
#pragma unroll
    for (int i = 0; i < 4; ++i) {
        const int dr = (t >> 4) + i * 16;
        const int sc = (t & 15) * 4;
        ushort4 oh, ol;
        oh.x = th[sc + 0][dr]; ol.x = tl[sc + 0][dr];
        oh.y = th[sc + 1][dr]; ol.y = tl[sc + 1][dr];
        oh.z = th[sc + 2][dr]; ol.z = tl[sc + 2][dr];
        oh.w = th[sc + 3][dr]; ol.w = tl[sc + 3][dr];
        const size_t o = ((size_t)(b * NKV + u) * HD + dv0 + dr) * S + s0 + sc;
        *reinterpret_cast<ushort4*>(&Yh[o]) = oh;
        *reinterpret_cast<ushort4*>(&Yl[o]) = ol;
    }
}

// ---------------------------------------------------------------------------
// Flash attention, double-bf16 hi/lo MFMA, fp32 online softmax.
// SWAPPED QK^T: a = mfma(K, Q) so each lane's 8 S-values all belong to ONE
// q-row (lc). Row max/sum = 7 in-lane ops + 2 shfl_xor. P written as packed
// ds_write_b64. Per-lane m/l state; rescale/epilogue broadcast via shfl.
// Staging/T14/defer-max structure identical to round 6.
// ---------------------------------------------------------------------------
constexpr int QTILE = 64, KT = 32;

__global__ __launch_bounds__(256)
void flash_mfma_kernel(const u16* __restrict__ Qh, const u16* __restrict__ Ql,
                       const u16* __restrict__ Kh, const u16* __restrict__ Kl,
                       const u16* __restrict__ Vh, const u16* __restrict__ Vl,
                       u16* __restrict__ Oh, u16* __restrict__ Ol)
{
    __shared__ alignas(16) u16 smem[23552];
    u16* KsH = smem;
    u16* KsL = smem + 4096;
    u16* VtH = smem + 8192;
    u16* VtL = smem + 13312;
    u16* PH  = smem + 18432;
    u16* PL  = smem + 20992;

    const int t  = threadIdx.x;
    const int w  = t >> 6;
    const int ln = t & 63;
    const int lg = ln >> 4;             // lane group g: 0..3
    const int lc = ln & 15;             // 0..15

    const int qt = (int)gridDim.x - 1 - (int)blockIdx.x;   // heavy tiles first
    const int q0 = qt * QTILE;
    const int bh = blockIdx.y;
    const int b  = bh / NH, h = bh % NH, u = h / GRP;

    const size_t qbase = (size_t)(b * NH + h) * S * HD;
    const size_t kbase = (size_t)(b * NKV + u) * S * HD;
    const size_t vbase = (size_t)(b * NKV + u) * HD * S;

    // ---- stage Q hi/lo tiles (swizzled), pull per-wave fragments ----
    {
        u16* QsH = smem;
        u16* QsL = smem + 8192;
#pragma unroll
        for (int i = 0; i < 4; ++i) {
            const int r = (t >> 4) + i * 16;
            const int blk = t & 15;
            const size_t src = qbase + (size_t)(q0 + r) * HD + blk * 8;
            const int dst = r * 128 + ((blk ^ (r & 7)) * 8);
            *reinterpret_cast<short8*>(&QsH[dst]) =
                *reinterpret_cast<const short8*>(&Qh[src]);
            *reinterpret_cast<short8*>(&QsL[dst]) =
                *reinterpret_cast<const short8*>(&Ql[src]);
        }
        __syncthreads();
    }
    short8 qah[4], qal[4];
#pragma unroll
    for (int ks = 0; ks < 4; ++ks) {
        const int qr = w * 16 + lc;
        const int off = qr * 128 + (((ks * 4 + lg) ^ (qr & 7)) * 8);
        qah[ks] = *reinterpret_cast<const short8*>(&smem[off]);
        qal[ks] = *reinterpret_cast<const short8*>(&smem[8192 + off]);
    }
    __syncthreads();

    f32x4 o[8];
#pragma unroll
    for (int i = 0; i < 8; ++i) o[i] = (f32x4){0.f, 0.f, 0.f, 0.f};
    // per-lane online-softmax state for q-row (qw0 + lc), replicated over groups
    float m_run = -1e30f, l_run = 0.f;

    u16* PwH = PH + w * 640;
    u16* PwL = PL + w * 640;
    const int qw0 = q0 + w * 16;
    const int nkt = q0 / KT + 2;        // block-uniform trip count

    // staging thread roles + precomputed LDS dests
    const int sr_k = t >> 4;            // 0..15
    const int sb_k = t & 15;
    const int sr_v = t >> 2;            // 0..63
    const int sb_v = t & 3;
    const int dKsw = (sb_k ^ (sr_k & 7)) * 8;
    const int dK0  = sr_k * 128 + dKsw;
    const int dK1  = (sr_k + 16) * 128 + dKsw;
    const int dV0  = sr_v * 40 + sb_v * 8;
    const int dV1  = (sr_v + 64) * 40 + sb_v * 8;

    short8 stg[8];
#define LOADTILE(K0)                                                          \
    {                                                                         \
        const size_t ksrc = kbase + (size_t)((K0) + sr_k) * HD + sb_k * 8;    \
        stg[0] = *reinterpret_cast<const short8*>(&Kh[ksrc]);                 \
        stg[1] = *reinterpret_cast<const short8*>(&Kh[ksrc + 16 * HD]);       \
        stg[2] = *reinterpret_cast<const short8*>(&Kl[ksrc]);                 \
        stg[3] = *reinterpret_cast<const short8*>(&Kl[ksrc + 16 * HD]);       \
        const size_t vsrc = vbase + (size_t)sr_v * S + (K0) + sb_v * 8;       \
        stg[4] = *reinterpret_cast<const short8*>(&Vh[vsrc]);                 \
        stg[5] = *reinterpret_cast<const short8*>(&Vh[vsrc + (size_t)64 * S]);\
        stg[6] = *reinterpret_cast<const short8*>(&Vl[vsrc]);                 \
        stg[7] = *reinterpret_cast<const short8*>(&Vl[vsrc + (size_t)64 * S]);\
    }

    LOADTILE(0);

    for (int kt = 0; kt < nkt; ++kt) {
        const int k0 = kt * KT;
        *reinterpret_cast<short8*>(&KsH[dK0]) = stg[0];
        *reinterpret_cast<short8*>(&KsH[dK1]) = stg[1];
        *reinterpret_cast<short8*>(&KsL[dK0]) = stg[2];
        *reinterpret_cast<short8*>(&KsL[dK1]) = stg[3];
        *reinterpret_cast<short8*>(&VtH[dV0]) = stg[4];
        *reinterpret_cast<short8*>(&VtH[dV1]) = stg[5];
        *reinterpret_cast<short8*>(&VtL[dV0]) = stg[6];
        *reinterpret_cast<short8*>(&VtL[dV1]) = stg[7];
        __syncthreads();

        // T14: issue next tile's global loads now; they fly under compute
        if (kt + 1 < nkt) LOADTILE(k0 + KT);

        if (k0 <= qw0 + 15) {           // wave-level causal skip
            // ---- S^T tiles: a0 = K[0:16).Q^T, a1 = K[16:32).Q^T ----
            f32x4 a0 = {0.f, 0.f, 0.f, 0.f}, a1 = {0.f, 0.f, 0.f, 0.f};
            __builtin_amdgcn_s_setprio(1);
#pragma unroll
            for (int ks = 0; ks < 4; ++ks) {
                const int r0 = lc, r1 = 16 + lc;
                const int o0b = r0 * 128 + (((ks * 4 + lg) ^ (r0 & 7)) * 8);
                const int o1b = r1 * 128 + (((ks * 4 + lg) ^ (r1 & 7)) * 8);
                const short8 kb0h = *reinterpret_cast<const short8*>(&KsH[o0b]);
                const short8 kb0l = *reinterpret_cast<const short8*>(&KsL[o0b]);
                const short8 kb1h = *reinterpret_cast<const short8*>(&KsH[o1b]);
                const short8 kb1l = *reinterpret_cast<const short8*>(&KsL[o1b]);
                // swapped operand order: A = K, B = Q
                a0 = __builtin_amdgcn_mfma_f32_16x16x32_bf16(kb0h, qal[ks], a0, 0, 0, 0);
                a0 = __builtin_amdgcn_mfma_f32_16x16x32_bf16(kb0l, qah[ks], a0, 0, 0, 0);
                a0 = __builtin_amdgcn_mfma_f32_16x16x32_bf16(kb0h, qah[ks], a0, 0, 0, 0);
                a1 = __builtin_amdgcn_mfma_f32_16x16x32_bf16(kb1h, qal[ks], a1, 0, 0, 0);
                a1 = __builtin_amdgcn_mfma_f32_16x16x32_bf16(kb1l, qah[ks], a1, 0, 0, 0);
                a1 = __builtin_amdgcn_mfma_f32_16x16x32_bf16(kb1h, qah[ks], a1, 0, 0, 0);
            }
            __builtin_amdgcn_s_setprio(0);

            // lane holds S[k0 + g*4 + r][qg] (a0) and S[k0+16+g*4+r][qg] (a1)
            const int qg = qw0 + lc;
            const int kb = k0 + lg * 4;
            if (k0 + KT - 1 > qw0) {    // diagonal: mask k > q
#pragma unroll
                for (int r = 0; r < 4; ++r) {
                    if (kb + r > qg)      a0[r] = -1e30f;
                    if (kb + 16 + r > qg) a1[r] = -1e30f;
                }
            }

            // ---- row max: in-lane tree + 2 shfl ----
            float mx = fmaxf(fmaxf(fmaxf(a0[0], a0[1]), fmaxf(a0[2], a0[3])),
                             fmaxf(fmaxf(a1[0], a1[1]), fmaxf(a1[2], a1[3])));
            mx = fmaxf(mx, __shfl_xor(mx, 16, 64));
            mx = fmaxf(mx, __shfl_xor(mx, 32, 64));

            // defer-max (THR=8)
            const bool resc_needed = __any((int)(mx > m_run + 8.0f));
            float mn = m_run, rsc = 1.0f;
            if (resc_needed) {
                mn  = fmaxf(m_run, mx);
                rsc = __expf(m_run - mn);
            }

            // ---- p = exp(s - mn), row sum ----
            float p0[4], p1[4];
            float rs = 0.f;
#pragma unroll
            for (int r = 0; r < 4; ++r) {
                p0[r] = __expf(a0[r] - mn);
                p1[r] = __expf(a1[r] - mn);
                rs += p0[r] + p1[r];
            }
            rs += __shfl_xor(rs, 16, 64);
            rs += __shfl_xor(rs, 32, 64);
            l_run = l_run * rsc + rs;
            m_run = mn;

            if (resc_needed) {
                float rr[4];
#pragma unroll
                for (int r = 0; r < 4; ++r)
                    rr[r] = __shfl(rsc, lg * 4 + r, 64);  // group-0 lane of that row
#pragma unroll
                for (int nt = 0; nt < 8; ++nt)
#pragma unroll
                    for (int r = 0; r < 4; ++r) o[nt][r] *= rr[r];
            }

            // ---- P -> LDS, packed b64 (row lc, k = g*4..g*4+3 [+16]) ----
            {
                u16 h0[4], h1[4], l0[4], l1[4];
#pragma unroll
                for (int r = 0; r < 4; ++r) {
                    h0[r] = f2bf(p0[r]); l0[r] = f2bf(p0[r] - bf2f(h0[r]));
                    h1[r] = f2bf(p1[r]); l1[r] = f2bf(p1[r] - bf2f(h1[r]));
                }
                const int base = lc * 40 + lg * 4;
                uint2 v;
                v.x = (unsigned)h0[0] | ((unsigned)h0[1] << 16);
                v.y = (unsigned)h0[2] | ((unsigned)h0[3] << 16);
                *reinterpret_cast<uint2*>(&PwH[base]) = v;
                v.x = (unsigned)h1[0] | ((unsigned)h1[1] << 16);
                v.y = (unsigned)h1[2] | ((unsigned)h1[3] << 16);
                *reinterpret_cast<uint2*>(&PwH[base + 16]) = v;
                v.x = (unsigned)l0[0] | ((unsigned)l0[1] << 16);
                v.y = (unsigned)l0[2] | ((unsigned)l0[3] << 16);
                *reinterpret_cast<uint2*>(&PwL[base]) = v;
                v.x = (unsigned)l1[0] | ((unsigned)l1[1] << 16);
                v.y = (unsigned)l1[2] | ((unsigned)l1[3] << 16);
                *reinterpret_cast<uint2*>(&PwL[base + 16]) = v;
            }
            asm volatile("s_waitcnt lgkmcnt(0)" ::: "memory");

            // ---- O += P.V ----
            const short8 pah = *reinterpret_cast<const short8*>(&PwH[lc * 40 + lg * 8]);
            const short8 pal = *reinterpret_cast<const short8*>(&PwL[lc * 40 + lg * 8]);
            __builtin_amdgcn_s_setprio(1);
#pragma unroll
            for (int nt = 0; nt < 8; ++nt) {
                const int dvo = (nt * 16 + lc) * 40 + lg * 8;
                const short8 vbh = *reinterpret_cast<const short8*>(&VtH[dvo]);
                const short8 vbl = *reinterpret_cast<const short8*>(&VtL[dvo]);
                o[nt] = __builtin_amdgcn_mfma_f32_16x16x32_bf16(pal, vbh, o[nt], 0, 0, 0);
                o[nt] = __builtin_amdgcn_mfma_f32_16x16x32_bf16(pah, vbl, o[nt], 0, 0, 0);
                o[nt] = __builtin_amdgcn_mfma_f32_16x16x32_bf16(pah, vbh, o[nt], 0, 0, 0);
            }
            __builtin_amdgcn_s_setprio(0);
        }
        __syncthreads();
    }
#undef LOADTILE

    // epilogue: broadcast 1/l for the 4 D-rows this lane writes
    const float linv = 1.f / l_run;
    float invl[4];
#pragma unroll
    for (int r = 0; r < 4; ++r) invl[r] = __shfl(linv, lg * 4 + r, 64);
#pragma unroll
    for (int nt = 0; nt < 8; ++nt) {
#pragma unroll
        for (int r = 0; r < 4; ++r) {
            const float v = o[nt][r] * invl[r];
            const size_t off =
                (size_t)(b * S + qw0 + lg * 4 + r) * (NH * HD) + h * HD + nt * 16 + lc;
            const u16 hv = f2bf(v);
            Oh[off] = hv;
            Ol[off] = f2bf(v - bf2f(hv));
        }
    }
}

} // anonymous namespace

// ---------------------------------------------------------------------------
// Workspace layout identical to round 4 (120 MiB with aliasing).
// ---------------------------------------------------------------------------
extern "C" void kernel_launch(void* const* d_in, const int* in_sizes, int n_in,
                              void* d_out, int out_size, void* d_ws, size_t ws_size,
                              hipStream_t stream)
{
    const float* hidden = (const float*)d_in[0];
    const float* Wq = (const float*)d_in[2];
    const float* Wk = (const float*)d_in[3];
    const float* Wv = (const float*)d_in[4];
    const float* Wo = (const float*)d_in[5];
    float* out = (float*)d_out;

    char* wsb = (char*)d_ws;
    u16*   hid_hi  = (u16*)(wsb);
    u16*   hid_lo  = (u16*)(wsb + 16777216);
    float* qkv_f   = (float*)(wsb + 33554432);
    u16*   k_hi    = (u16*)(wsb + 83886080);
    u16*   k_lo    = (u16*)(wsb + 88080384);
    u16*   v_hi    = (u16*)(wsb + 92274688);
    u16*   v_lo    = (u16*)(wsb + 96468992);
    u16*   wT_hi   = (u16*)(wsb + 100663296);
    u16*   wT_lo   = (u16*)(wsb + 113246208);
    // aliases
    u16* q_hi    = hid_hi;                     // hid dead after GEMM1
    u16* q_lo    = hid_lo;
    u16* attn_hi = (u16*)(wsb + 33554432);     // qkv_f dead after rope/vcast
    u16* attn_lo = (u16*)(wsb + 50331648);
    u16* woT_hi  = wT_hi;                      // WqkvT dead after GEMM1
    u16* woT_lo  = wT_lo;

    const dim3 blk(256);

    split_cast_kernel<<<dim3(8192), blk, 0, stream>>>(hidden, hid_hi, hid_lo, 2097152);
    wcast_t_kernel<<<dim3(32, 32), blk, 0, stream>>>(Wq, wT_hi, wT_lo, 2048, 0);
    wcast_t_kernel<<<dim3(8, 32),  blk, 0, stream>>>(Wk, wT_hi, wT_lo, 512, 2048);
    wcast_t_kernel<<<dim3(8, 32),  blk, 0, stream>>>(Wv, wT_hi, wT_lo, 512, 2560);
    hgemm_hilo_kernel<<<dim3(24, 32), blk, 0, stream>>>(
        hid_hi, hid_lo, wT_hi, wT_lo, qkv_f, 4096, 3072, 2048);
    wcast_t_kernel<<<dim3(32, 32), blk, 0, stream>>>(Wo, woT_hi, woT_lo, 2048, 0);
    const int qpairs = 4096 * NH * 64;
    const int kpairs = 4096 * NKV * 64;
    rope_cast_kernel<<<dim3(qpairs / 256), blk, 0, stream>>>(
        qkv_f, 3072, 0, q_hi, q_lo, NH, qpairs, 0.08838834764831845f);
    rope_cast_kernel<<<dim3(kpairs / 256), blk, 0, stream>>>(
        qkv_f, 3072, 2048, k_hi, k_lo, NKV, kpairs, 1.0f);
    vcast_kernel<<<dim3(32, 2, 8), blk, 0, stream>>>(
        qkv_f, 3072, 2560, v_hi, v_lo);
    flash_mfma_kernel<<<dim3(S / QTILE, B * NH), blk, 0, stream>>>(
        q_hi, q_lo, k_hi, k_lo, v_hi, v_lo, attn_hi, attn_lo);
    hgemm_hilo_kernel<<<dim3(16, 32), blk, 0, stream>>>(
        attn_hi, attn_lo, woT_hi, woT_lo, out, 4096, 2048, 2048);
}